// Round 2
// baseline (212.257 us; speedup 1.0000x reference)
//
#include <hip/hip_runtime.h>
#include <cfloat>
#include <cmath>

#define K_EMB 1024
#define DIM 64
#define TT 2048
#define NTOT 65536

// Block = one (b, t-tile of 64). 256 threads as 16(t) x 16(k), 4x4 micro-tile.
// ZERO d_ws usage: counts accumulate into out_avg region, distsum into out_commit.
__global__ __launch_bounds__(256) void argmin_kernel(
    const float* __restrict__ x,       // [B][D][T]
    const float* __restrict__ embed,   // [K][D] row-major
    float* __restrict__ out_q,         // [B][D][T]
    float* __restrict__ out_idx,       // [B][T] (as float)
    float* __restrict__ counts,        // = out_avg region, pre-zeroed
    float* __restrict__ distsum)       // = out_commit slot, pre-zeroed
{
    __shared__ float xs[DIM][68];      // [j][tt]; pad 68: float4-aligned rows, 2-way banks
    __shared__ float es[DIM][68];      // [j][kk]; reused for quantized gather at the end
    __shared__ float pe2[64][5];       // per-chunk ||e||^2 partials [code][seg]
    __shared__ float red_s[64][17];
    __shared__ int   red_i[64][17];
    __shared__ int   idx_sh[64];
    __shared__ float md_sh[64];

    const int tid = threadIdx.x;
    const int bid = blockIdx.x;
    const int b  = bid >> 5;           // 32 t-tiles per batch row
    const int t0 = (bid & 31) << 6;

    // stage x tile: xs[j][tt] = x[b][j][t0+tt]  (coalesced float4, conflict-free)
    {
        const int c4 = (tid & 15) * 4;
        #pragma unroll
        for (int r = tid >> 4; r < DIM; r += 16) {
            const float4 v = *(const float4*)(x + (size_t)(b * DIM + r) * TT + t0 + c4);
            *(float4*)&xs[r][c4] = v;
        }
    }

    const int ti = tid & 15;           // t sub-block
    const int tj = tid >> 4;           // k sub-block
    float bestS[4] = {FLT_MAX, FLT_MAX, FLT_MAX, FLT_MAX};
    int   bestI[4] = {0, 0, 0, 0};

    for (int kc = 0; kc < K_EMB / 64; ++kc) {
        __syncthreads();               // B1: es/pe2 free (xs staged at kc==0)
        // stage es transposed: es[j][kk] = embed[kc*64+kk][j] (coalesced 1KB row reads)
        {
            const int g  = tid & 15;   // j-group
            const int r0 = tid >> 4;   // code row base
            #pragma unroll
            for (int i = 0; i < 4; ++i) {
                const int r = r0 + 16 * i;
                const float4 v = *(const float4*)(embed + (size_t)(kc * 64 + r) * DIM + g * 4);
                es[g * 4 + 0][r] = v.x;
                es[g * 4 + 1][r] = v.y;
                es[g * 4 + 2][r] = v.z;
                es[g * 4 + 3][r] = v.w;
            }
        }
        __syncthreads();               // B2: es ready
        // per-chunk ||e||^2 partials: code c = tid&63, j-segment = tid>>6
        {
            const int c   = tid & 63;
            const int seg = tid >> 6;
            float s = 0.f;
            #pragma unroll
            for (int j = seg * 16; j < seg * 16 + 16; ++j) {
                const float v = es[j][c];
                s += v * v;
            }
            pe2[c][seg] = s;
        }
        __syncthreads();               // B3: pe2 ready

        float acc[4][4] = {{0.f}};
        #pragma unroll 8
        for (int j = 0; j < DIM; ++j) {
            const float4 xv = *(const float4*)&xs[j][ti * 4];
            const float4 ev = *(const float4*)&es[j][tj * 4];
            acc[0][0] += xv.x * ev.x; acc[0][1] += xv.x * ev.y;
            acc[0][2] += xv.x * ev.z; acc[0][3] += xv.x * ev.w;
            acc[1][0] += xv.y * ev.x; acc[1][1] += xv.y * ev.y;
            acc[1][2] += xv.y * ev.z; acc[1][3] += xv.y * ev.w;
            acc[2][0] += xv.z * ev.x; acc[2][1] += xv.z * ev.y;
            acc[2][2] += xv.z * ev.z; acc[2][3] += xv.z * ev.w;
            acc[3][0] += xv.w * ev.x; acc[3][1] += xv.w * ev.y;
            acc[3][2] += xv.w * ev.z; acc[3][3] += xv.w * ev.w;
        }

        const int kbase = kc * 64 + tj * 4;
        #pragma unroll
        for (int q = 0; q < 4; ++q) {
            const int c = tj * 4 + q;
            const float e2 = pe2[c][0] + pe2[c][1] + pe2[c][2] + pe2[c][3];
            #pragma unroll
            for (int a = 0; a < 4; ++a) {
                // s = ||e||^2 - 2 x.e ; strict < + ascending-k order keeps first-min
                const float s = e2 - 2.f * acc[a][q];
                if (s < bestS[a]) { bestS[a] = s; bestI[a] = kbase + q; }
            }
        }
    }

    __syncthreads();                   // B_r1: all done reading es/pe2
    #pragma unroll
    for (int a = 0; a < 4; ++a) {
        const int nl = ti * 4 + a;
        red_s[nl][tj] = bestS[a];
        red_i[nl][tj] = bestI[a];
    }
    __syncthreads();                   // B_r2

    if (tid < 64) {
        float bs = red_s[tid][0]; int bi = red_i[tid][0];
        #pragma unroll
        for (int q = 1; q < 16; ++q) {
            const float s = red_s[tid][q]; const int i = red_i[tid][q];
            if (s < bs || (s == bs && i < bi)) { bs = s; bi = i; }
        }
        float x2 = 0.f;
        #pragma unroll
        for (int j = 0; j < DIM; ++j) { const float v = xs[j][tid]; x2 += v * v; }
        md_sh[tid]  = x2 + bs;         // ||x - e_best||^2
        idx_sh[tid] = bi;
        out_idx[b * TT + t0 + tid] = (float)bi;
        atomicAdd(&counts[bi], 1.0f);
    }
    __syncthreads();                   // B_r3: idx_sh/md_sh ready; es reusable

    if (tid == 0) {
        float s = 0.f;
        #pragma unroll
        for (int q = 0; q < 64; ++q) s += md_sh[q];
        atomicAdd(distsum, s);
    }

    // gather quantized into es (reused): es[j][tt] = embed[idx_sh[tt]][j]
    {
        const int g  = tid & 15;
        const int r0 = tid >> 4;
        #pragma unroll
        for (int i = 0; i < 4; ++i) {
            const int tt = r0 + 16 * i;
            const float4 v = *(const float4*)(embed + (size_t)idx_sh[tt] * DIM + g * 4);
            es[g * 4 + 0][tt] = v.x;
            es[g * 4 + 1][tt] = v.y;
            es[g * 4 + 2][tt] = v.z;
            es[g * 4 + 3][tt] = v.w;
        }
    }
    __syncthreads();                   // B_r4

    // coalesced transposed write: out_q[b][j][t0+tc*4..+3]
    for (int p = tid; p < 1024; p += 256) {
        const int j  = p >> 4;
        const int tc = p & 15;
        float4 w;
        w.x = es[j][tc * 4 + 0];
        w.y = es[j][tc * 4 + 1];
        w.z = es[j][tc * 4 + 2];
        w.w = es[j][tc * 4 + 3];
        *(float4*)(out_q + (size_t)(b * DIM + j) * TT + t0 + tc * 4) = w;
    }
}

// finalize: in-place counts->avg_probs, perplexity, usage, commitment
__global__ __launch_bounds__(1024) void finalize_kernel(
    float* __restrict__ avg,           // in: counts, out: probs
    float* __restrict__ commit_slot,   // in: distsum, out: commitment loss
    float* __restrict__ out_perp,
    float* __restrict__ out_usage)
{
    __shared__ float s_ent[1024];
    __shared__ float s_use[1024];
    const int k = threadIdx.x;
    const float p = avg[k] * (1.0f / (float)NTOT);
    avg[k] = p;
    s_ent[k] = p * logf(p + 1e-10f);
    s_use[k] = p * logf(p * 1024.f + 1e-10f);
    __syncthreads();
    for (int off = 512; off > 0; off >>= 1) {
        if (k < off) { s_ent[k] += s_ent[k + off]; s_use[k] += s_use[k + off]; }
        __syncthreads();
    }
    if (k == 0) {
        const float ds = commit_slot[0];
        *out_perp    = expf(-s_ent[0]);
        *out_usage   = s_use[0];
        commit_slot[0] = 0.25f * ds * (1.0f / ((float)NTOT * (float)DIM));
    }
}

extern "C" void kernel_launch(void* const* d_in, const int* in_sizes, int n_in,
                              void* d_out, int out_size, void* d_ws, size_t ws_size,
                              hipStream_t stream) {
    const float* x     = (const float*)d_in[0];
    const float* embed = (const float*)d_in[1];

    float* out        = (float*)d_out;
    float* out_q      = out;             // 4194304
    float* out_commit = out + 4194304;   // 1   (used as distsum accumulator first)
    float* out_perp   = out + 4194305;   // 1
    float* out_avg    = out + 4194306;   // 1024 (used as counts accumulator first)
    float* out_idx    = out + 4195330;   // 65536
    // usage at out + 4260866 (written by finalize via pointer below)

    // zero the accumulator region (commit, perp, avg) — d_out is ours, no ws needed
    hipMemsetAsync(out_commit, 0, 1026 * sizeof(float), stream);
    argmin_kernel<<<1024, 256, 0, stream>>>(x, embed, out_q, out_idx, out_avg, out_commit);
    finalize_kernel<<<1, 1024, 0, stream>>>(out_avg, out_commit, out_perp, out + 4260866);
}